// Round 5
// baseline (155.678 us; speedup 1.0000x reference)
//
#include <hip/hip_runtime.h>

#define NPTS 65536
#define MPTS 65536
#define FSTR 72            // featB row stride in shorts (144 B, 16B-aligned)

typedef __attribute__((ext_vector_type(8))) short bf16x8;
typedef __attribute__((ext_vector_type(4))) float f32x4;

__device__ __forceinline__ float bflo(unsigned int u){ union{unsigned int i; float f;} v; v.i = u<<16; return v.f; }
__device__ __forceinline__ float bfhi(unsigned int u){ union{unsigned int i; float f;} v; v.i = u & 0xffff0000u; return v.f; }
__device__ __forceinline__ unsigned short f2bf(float f){
  union{float f; unsigned int i;} v; v.f=f;
  unsigned int r = v.i + 0x7fffu + ((v.i>>16)&1u);  // RNE
  return (unsigned short)(r>>16);
}

#define MFMA32(a,b,c) __builtin_amdgcn_mfma_f32_16x16x32_bf16((a),(b),(c),0,0,0)

// ---- pack x[64][N] + pos[3][N] -> P2[N][72] bf16; blocks 0..10 also pack weights ----
__global__ __launch_bounds__(256) void pack_all(
    const float* __restrict__ x, const float* __restrict__ pos,
    const float* __restrict__ W1, const float* __restrict__ W2,
    unsigned short* __restrict__ P2,
    unsigned short* __restrict__ W1F,    // 12 frags: kt0..1 x nt0..3 (c<64), then 4 tail frags (c=64..66)
    unsigned short* __restrict__ W2F) {  // 32 frags: nt0..3 x ot0..7, j<4 data, j>=4 zero
  __shared__ unsigned int tile[64 * 37];
  const int t = threadIdx.x;
  const int n0 = blockIdx.x * 64;
  const int p = t & 63, cq = t >> 6;
  const int n = n0 + p;
  #pragma unroll
  for (int jj = 0; jj < 8; ++jj) {
    const int c = cq * 16 + 2 * jj;
    const unsigned int lo = f2bf(x[(size_t)c * NPTS + n]);
    const unsigned int hi = f2bf(x[(size_t)(c + 1) * NPTS + n]);
    tile[p * 37 + cq * 8 + jj] = lo | (hi << 16);
  }
  if (cq == 0) {
    const unsigned int a = f2bf(pos[n]);
    const unsigned int b = f2bf(pos[NPTS + n]);
    const unsigned int cc = f2bf(pos[2 * NPTS + n]);
    tile[p * 37 + 32] = a | (b << 16);
    tile[p * 37 + 33] = cc;
    tile[p * 37 + 34] = 0u;
    tile[p * 37 + 35] = 0u;
  }
  __syncthreads();
  unsigned int* Pd = (unsigned int*)(P2 + (size_t)n0 * FSTR);
  #pragma unroll
  for (int i = 0; i < 9; ++i) {
    const int u = t + i * 256;
    const int nl = u / 36, d = u - nl * 36;
    Pd[u] = tile[nl * 37 + d];
  }
  // ---- weight fragment images ----
  const int wid = blockIdx.x * 256 + t;
  if (wid < 768) {                               // W1F: 12 frags x 64 lanes
    const int f = wid >> 6, lane = wid & 63;
    const int q = lane >> 4, lr = lane & 15;
    if (f < 8) {                                 // main: kt 0..1, c = kt*32+q*8+j (<64)
      const int kt = f >> 2, nt = f & 3;
      #pragma unroll
      for (int j = 0; j < 8; ++j)
        W1F[wid*8 + j] = f2bf(W1[(nt*16 + lr)*67 + kt*32 + q*8 + j]);
    } else {                                     // tail: c = 64+q*4+j (j<4), zero-padded
      const int nt = f - 8;
      #pragma unroll
      for (int j = 0; j < 8; ++j) {
        const int c = 64 + q*4 + j;
        W1F[wid*8 + j] = (j < 4 && c < 67) ? f2bf(W1[(nt*16 + lr)*67 + c]) : (unsigned short)0;
      }
    }
  } else if (wid < 768 + 2048) {                 // W2F: 32 frags x 64 lanes
    const int gg = wid - 768;
    const int g = gg >> 6, lane = gg & 63;
    const int q = lane >> 4, lr = lane & 15;
    const int nt = g >> 3, ot = g & 7;
    #pragma unroll
    for (int j = 0; j < 8; ++j)
      W2F[gg*8 + j] = (j < 4) ? f2bf(W2[(ot*16 + lr)*64 + nt*16 + q*4 + j]) : (unsigned short)0;
  }
}

// ---- fused gather -> MLP1(relu) -> MLP2 -> max over K; hidden stays in registers ----
__global__ __launch_bounds__(256, 4) void pointnet_mfma(
    const unsigned short* __restrict__ P2,   // [N][72] bf16
    const float* __restrict__ sup,           // [3][M] fp32
    const unsigned short* __restrict__ W1F,
    const float* __restrict__ b1,
    const unsigned short* __restrict__ W2F,
    const float* __restrict__ b2,
    const int* __restrict__ indices,         // [M][16]
    float* __restrict__ out) {               // [128][M] fp32
  __shared__ __align__(16) unsigned short featB[256 * FSTR];  // 36,864 B -> 4 blocks/CU

  const int t = threadIdx.x;
  const int m0 = blockIdx.x * 16;
  const int lane = t & 63, w = t >> 6, quad = lane >> 4, lr = lane & 15;

  // ---- gather: thread t owns point t (wave-private LDS rows, no barrier) ----
  {
    const int idx = indices[m0*16 + t];
    const uint4* src = (const uint4*)(P2 + (size_t)idx * FSTR);
    uint4 u[9];
    #pragma unroll
    for (int i = 0; i < 9; ++i) u[i] = src[i];
    const int mm = m0 + (t >> 4);
    const float s0 = sup[mm], s1 = sup[MPTS + mm], s2 = sup[2*MPTS + mm];
    const float p0 = bflo(u[8].x), p1 = bfhi(u[8].x), p2 = bflo(u[8].y);
    u[8].x = (unsigned int)f2bf(p0 - s0) | ((unsigned int)f2bf(p1 - s1) << 16);
    u[8].y = (unsigned int)f2bf(p2 - s2);   // col 67 = 0
    u[8].z = 0u; u[8].w = 0u;               // cols 68..71 = 0
    uint4* dst = (uint4*)(featB + t * FSTR);
    #pragma unroll
    for (int i = 0; i < 9; ++i) dst[i] = u[i];
  }

  // ---- stage 1: D1[h][p] = W1 . feat   (A = W1 frags, B = feat frags) ----
  const f32x4 fz = {0.f, 0.f, 0.f, 0.f};
  f32x4 acc1[4][4];                          // [nt = h-tile][pt = point-tile]
  #pragma unroll
  for (int nt = 0; nt < 4; ++nt)
    #pragma unroll
    for (int pt = 0; pt < 4; ++pt) acc1[nt][pt] = fz;

  #pragma unroll
  for (int kt = 0; kt < 2; ++kt) {           // c = 0..63
    bf16x8 wa[4];
    #pragma unroll
    for (int nt = 0; nt < 4; ++nt)
      wa[nt] = ((const bf16x8*)W1F)[(kt*4 + nt)*64 + lane];
    bf16x8 bf[4];
    #pragma unroll
    for (int pt = 0; pt < 4; ++pt)
      bf[pt] = *(const bf16x8*)&featB[(w*64 + pt*16 + lr)*FSTR + kt*32 + quad*8];
    #pragma unroll
    for (int nt = 0; nt < 4; ++nt)
      #pragma unroll
      for (int pt = 0; pt < 4; ++pt)
        acc1[nt][pt] = MFMA32(wa[nt], bf[pt], acc1[nt][pt]);
  }
  {                                          // tail c = 64..66 (A image zero elsewhere)
    bf16x8 wa16[4];
    #pragma unroll
    for (int nt = 0; nt < 4; ++nt)
      wa16[nt] = ((const bf16x8*)W1F)[(8 + nt)*64 + lane];
    bf16x8 bt[4];
    #pragma unroll
    for (int pt = 0; pt < 4; ++pt) {
      // j<4 slots: cols 64 + (quad&1)*4 + j ; quads 2,3 read valid garbage * zero-A
      const uint2 d = *(const uint2*)&featB[(w*64 + pt*16 + lr)*FSTR + 64 + (quad & 1)*4];
      union { unsigned int u[4]; bf16x8 v; } mk;
      mk.u[0] = d.x; mk.u[1] = d.y; mk.u[2] = 0u; mk.u[3] = 0u;
      bt[pt] = mk.v;
    }
    #pragma unroll
    for (int nt = 0; nt < 4; ++nt)
      #pragma unroll
      for (int pt = 0; pt < 4; ++pt)
        acc1[nt][pt] = MFMA32(wa16[nt], bt[pt], acc1[nt][pt]);
  }

  // ---- bias + relu + pack to bf16 pairs (h = nt*16 + quad*4 + r, p-col = lr) ----
  unsigned int dwpk[4][4][2];
  #pragma unroll
  for (int nt = 0; nt < 4; ++nt) {
    const float4 bb = *(const float4*)(b1 + nt*16 + quad*4);
    #pragma unroll
    for (int pt = 0; pt < 4; ++pt) {
      const float v0 = fmaxf(acc1[nt][pt][0] + bb.x, 0.f);
      const float v1 = fmaxf(acc1[nt][pt][1] + bb.y, 0.f);
      const float v2 = fmaxf(acc1[nt][pt][2] + bb.z, 0.f);
      const float v3 = fmaxf(acc1[nt][pt][3] + bb.w, 0.f);
      dwpk[nt][pt][0] = (unsigned int)f2bf(v0) | ((unsigned int)f2bf(v1) << 16);
      dwpk[nt][pt][1] = (unsigned int)f2bf(v2) | ((unsigned int)f2bf(v3) << 16);
    }
  }

  // ---- stage 2: D2[p][o] = H . W2^T, hidden direct from registers; k-max; store ----
  #pragma unroll
  for (int ot = 0; ot < 8; ++ot) {
    f32x4 a2[4];
    #pragma unroll
    for (int pt = 0; pt < 4; ++pt) a2[pt] = fz;
    #pragma unroll
    for (int nt = 0; nt < 4; ++nt) {         // h = nt*16 + quad*4 + j  (j<4 slots)
      const bf16x8 wb = ((const bf16x8*)W2F)[(nt*8 + ot)*64 + lane];
      #pragma unroll
      for (int pt = 0; pt < 4; ++pt) {
        union { unsigned int u[4]; bf16x8 v; } mk;
        mk.u[0] = dwpk[nt][pt][0]; mk.u[1] = dwpk[nt][pt][1];
        mk.u[2] = 0u; mk.u[3] = 0u;
        a2[pt] = MFMA32(mk.v, wb, a2[pt]);
      }
    }
    // k-max: rows p = quad*4+r of each pt-tile are the 16 neighbors of m = w*4+pt
    float vm[4];
    #pragma unroll
    for (int pt = 0; pt < 4; ++pt) {
      float v = fmaxf(fmaxf(a2[pt][0], a2[pt][1]), fmaxf(a2[pt][2], a2[pt][3]));
      v = fmaxf(v, __shfl_xor(v, 16));
      v = fmaxf(v, __shfl_xor(v, 32));
      vm[pt] = v;
    }
    // quad q stores tile pt=q -> full-lane store, block-local 64B out lines
    const float vq = (quad & 1) ? ((quad & 2) ? vm[3] : vm[1])
                                : ((quad & 2) ? vm[2] : vm[0]);
    const int o = ot*16 + lr;
    out[(size_t)o * MPTS + m0 + w*4 + quad] = vq + b2[o];
  }
}

// ---- fallback (ws too small): direct fp32 kernel, known-correct ----
__global__ __launch_bounds__(256) void pointnet_fallback(
    const float* __restrict__ x, const float* __restrict__ pos,
    const float* __restrict__ sup,
    const float* __restrict__ W1, const float* __restrict__ b1,
    const float* __restrict__ W2, const float* __restrict__ b2,
    const int* __restrict__ indices, float* __restrict__ out) {
  __shared__ float sfeat[16][68];
  __shared__ float shid[16][64];
  __shared__ float smax[4][128];
  __shared__ int sidx[16];
  const int t = threadIdx.x;
  const int m = blockIdx.x;
  if (t < 16) sidx[t] = indices[m*16 + t];
  const float sup0 = sup[m], sup1 = sup[MPTS + m], sup2 = sup[2*MPTS + m];
  __syncthreads();
  for (int u = t; u < 16*17; u += 256) {
    const int k = u / 17, c4 = (u - k*17) * 4;
    const int idx = sidx[k];
    float4 wv;
    if (c4 < 64) {
      wv.x = x[(size_t)(c4+0)*NPTS + idx]; wv.y = x[(size_t)(c4+1)*NPTS + idx];
      wv.z = x[(size_t)(c4+2)*NPTS + idx]; wv.w = x[(size_t)(c4+3)*NPTS + idx];
    } else {
      wv.x = pos[idx] - sup0; wv.y = pos[NPTS + idx] - sup1;
      wv.z = pos[2*NPTS + idx] - sup2; wv.w = 0.f;
    }
    *(float4*)&sfeat[k][c4] = wv;
  }
  const int h = t & 63, kg = t >> 6;
  float w1r[68];
  #pragma unroll
  for (int c = 0; c < 67; ++c) w1r[c] = W1[h*67 + c];
  w1r[67] = 0.f;
  const float bias1 = b1[h];
  __syncthreads();
  #pragma unroll
  for (int j = 0; j < 4; ++j) {
    const int k = kg*4 + j;
    float a = bias1;
    const float4* rr = (const float4*)sfeat[k];
    #pragma unroll
    for (int qq = 0; qq < 17; ++qq) {
      const float4 v = rr[qq];
      a += w1r[qq*4+0]*v.x + w1r[qq*4+1]*v.y + w1r[qq*4+2]*v.z + w1r[qq*4+3]*v.w;
    }
    shid[k][h] = fmaxf(a, 0.f);
  }
  const int ow = t & 63;
  float w2a[64], w2b[64];
  #pragma unroll
  for (int hh = 0; hh < 64; ++hh) { w2a[hh] = W2[ow*64 + hh]; w2b[hh] = W2[(ow+64)*64 + hh]; }
  __syncthreads();
  float mxa = -3.0e38f, mxb = -3.0e38f;
  #pragma unroll
  for (int j = 0; j < 4; ++j) {
    const int k = kg*4 + j;
    const float4* hr = (const float4*)shid[k];
    float pa = 0.f, pb = 0.f;
    #pragma unroll
    for (int qq = 0; qq < 16; ++qq) {
      const float4 v = hr[qq];
      pa += w2a[qq*4+0]*v.x + w2a[qq*4+1]*v.y + w2a[qq*4+2]*v.z + w2a[qq*4+3]*v.w;
      pb += w2b[qq*4+0]*v.x + w2b[qq*4+1]*v.y + w2b[qq*4+2]*v.z + w2b[qq*4+3]*v.w;
    }
    mxa = fmaxf(mxa, pa); mxb = fmaxf(mxb, pb);
  }
  smax[kg][ow] = mxa; smax[kg][64 + ow] = mxb;
  __syncthreads();
  if (t < 128) {
    out[(size_t)t * MPTS + m] =
        fmaxf(fmaxf(smax[0][t], smax[1][t]), fmaxf(smax[2][t], smax[3][t])) + b2[t];
  }
}

extern "C" void kernel_launch(void* const* d_in, const int* in_sizes, int n_in,
                              void* d_out, int out_size, void* d_ws, size_t ws_size,
                              hipStream_t stream) {
  const float* x   = (const float*)d_in[0];
  const float* pos = (const float*)d_in[1];
  const float* sup = (const float*)d_in[2];
  const float* W1  = (const float*)d_in[3];
  const float* b1  = (const float*)d_in[4];
  const float* W2  = (const float*)d_in[5];
  const float* b2  = (const float*)d_in[6];
  const int* indices = (const int*)d_in[7];
  float* out = (float*)d_out;

  const size_t P2_BYTES  = (size_t)NPTS * FSTR * 2;   // 9,437,184
  const size_t W1F_BYTES = 12 * 64 * 8 * 2;           // 12,288
  const size_t W2F_BYTES = 32 * 64 * 8 * 2;           // 32,768
  if (ws_size >= P2_BYTES + W1F_BYTES + W2F_BYTES) {
    unsigned short* P2  = (unsigned short*)d_ws;
    unsigned short* W1F = (unsigned short*)((char*)d_ws + P2_BYTES);
    unsigned short* W2F = (unsigned short*)((char*)d_ws + P2_BYTES + W1F_BYTES);
    pack_all<<<NPTS/64, 256, 0, stream>>>(x, pos, W1, W2, P2, W1F, W2F);
    pointnet_mfma<<<MPTS/16, 256, 0, stream>>>(P2, sup, W1F, b1, W2F, b2, indices, out);
  } else {
    pointnet_fallback<<<MPTS, 256, 0, stream>>>(x, pos, sup, W1, b1, W2, b2, indices, out);
  }
}

// Round 6
// 147.393 us; speedup vs baseline: 1.0562x; 1.0562x over previous
//
#include <hip/hip_runtime.h>

#define NPTS 65536
#define MPTS 65536
#define FSTR 72            // featB row stride in shorts (144 B, 16B-aligned)

typedef __attribute__((ext_vector_type(8))) short bf16x8;
typedef __attribute__((ext_vector_type(4))) float f32x4;

__device__ __forceinline__ float bflo(unsigned int u){ union{unsigned int i; float f;} v; v.i = u<<16; return v.f; }
__device__ __forceinline__ float bfhi(unsigned int u){ union{unsigned int i; float f;} v; v.i = u & 0xffff0000u; return v.f; }
__device__ __forceinline__ unsigned short f2bf(float f){
  union{float f; unsigned int i;} v; v.f=f;
  unsigned int r = v.i + 0x7fffu + ((v.i>>16)&1u);  // RNE
  return (unsigned short)(r>>16);
}

#define MFMA32(a,b,c) __builtin_amdgcn_mfma_f32_16x16x32_bf16((a),(b),(c),0,0,0)

// ---- pack x[64][N] + pos[3][N] -> P2[N][72] bf16; blocks 0..6 also pack weights ----
__global__ __launch_bounds__(256) void pack_all(
    const float* __restrict__ x, const float* __restrict__ pos,
    const float* __restrict__ W1, const float* __restrict__ W2,
    unsigned short* __restrict__ P2,
    unsigned short* __restrict__ W1F,    // 12 frags: kt0..1 x nt0..3 (c<64), then 4 tail frags (c=64..66)
    unsigned short* __restrict__ W2F) {  // 16 frags: kt0..1 x ot0..7, full K=32
  __shared__ unsigned int tile[64 * 37];
  const int t = threadIdx.x;
  const int n0 = blockIdx.x * 64;
  const int p = t & 63, cq = t >> 6;
  const int n = n0 + p;
  #pragma unroll
  for (int jj = 0; jj < 8; ++jj) {
    const int c = cq * 16 + 2 * jj;
    const unsigned int lo = f2bf(x[(size_t)c * NPTS + n]);
    const unsigned int hi = f2bf(x[(size_t)(c + 1) * NPTS + n]);
    tile[p * 37 + cq * 8 + jj] = lo | (hi << 16);
  }
  if (cq == 0) {
    const unsigned int a = f2bf(pos[n]);
    const unsigned int b = f2bf(pos[NPTS + n]);
    const unsigned int cc = f2bf(pos[2 * NPTS + n]);
    tile[p * 37 + 32] = a | (b << 16);
    tile[p * 37 + 33] = cc;
    tile[p * 37 + 34] = 0u;
    tile[p * 37 + 35] = 0u;
  }
  __syncthreads();
  unsigned int* Pd = (unsigned int*)(P2 + (size_t)n0 * FSTR);
  #pragma unroll
  for (int i = 0; i < 9; ++i) {
    const int u = t + i * 256;
    const int nl = u / 36, d = u - nl * 36;
    Pd[u] = tile[nl * 37 + d];
  }
  // ---- weight fragment images ----
  const int wid = blockIdx.x * 256 + t;
  if (wid < 768) {                               // W1F: 12 frags x 64 lanes
    const int f = wid >> 6, lane = wid & 63;
    const int q = lane >> 4, lr = lane & 15;
    if (f < 8) {                                 // main: A[m=lr][k=q*8+j], c = kt*32+q*8+j
      const int kt = f >> 2, nt = f & 3;
      #pragma unroll
      for (int j = 0; j < 8; ++j)
        W1F[wid*8 + j] = f2bf(W1[(nt*16 + lr)*67 + kt*32 + q*8 + j]);
    } else {                                     // tail: c = 64+q*4+j (j<4), zero elsewhere
      const int nt = f - 8;
      #pragma unroll
      for (int j = 0; j < 8; ++j) {
        const int c = 64 + q*4 + j;
        W1F[wid*8 + j] = (j < 4 && c < 67) ? f2bf(W1[(nt*16 + lr)*67 + c]) : (unsigned short)0;
      }
    }
  } else if (wid < 768 + 1024) {                 // W2F: 16 frags x 64 lanes, full K
    const int gg = wid - 768;
    const int g = gg >> 6, lane = gg & 63;       // g = kt*8 + ot
    const int q = lane >> 4, lr = lane & 15;
    const int kt = g >> 3, ot = g & 7;
    #pragma unroll
    for (int j = 0; j < 8; ++j)                  // B[k=q*8+j][n=lr] = W2[o=ot*16+lr][h=kt*32+q*8+j]
      W2F[gg*8 + j] = f2bf(W2[(ot*16 + lr)*64 + kt*32 + q*8 + j]);
  }
}

// ---- fused gather -> MLP1(relu) -> MLP2 -> max over K; zero barriers ----
__global__ __launch_bounds__(256, 4) void pointnet_mfma(
    const unsigned short* __restrict__ P2,   // [N][72] bf16
    const float* __restrict__ sup,           // [3][M] fp32
    const unsigned short* __restrict__ W1F,
    const float* __restrict__ b1,
    const unsigned short* __restrict__ W2F,
    const float* __restrict__ b2,
    const int* __restrict__ indices,         // [M][16]
    float* __restrict__ out) {               // [128][M] fp32
  __shared__ __align__(16) unsigned short featB[256 * FSTR];  // 36,864 B -> 4 blocks/CU
  // overlay: after stage 1, cols 0..63 of each row hold hidden bf16 (wave-private rows)

  const int t = threadIdx.x;
  const int m0 = blockIdx.x * 16;
  const int lane = t & 63, w = t >> 6, quad = lane >> 4, lr = lane & 15;

  // ---- gather: thread t owns point t (wave-private LDS rows, no barrier) ----
  {
    const int idx = indices[m0*16 + t];
    const uint4* src = (const uint4*)(P2 + (size_t)idx * FSTR);
    uint4 u[9];
    #pragma unroll
    for (int i = 0; i < 9; ++i) u[i] = src[i];
    const int mm = m0 + (t >> 4);
    const float s0 = sup[mm], s1 = sup[MPTS + mm], s2 = sup[2*MPTS + mm];
    const float p0 = bflo(u[8].x), p1 = bfhi(u[8].x), p2 = bflo(u[8].y);
    u[8].x = (unsigned int)f2bf(p0 - s0) | ((unsigned int)f2bf(p1 - s1) << 16);
    u[8].y = (unsigned int)f2bf(p2 - s2);   // col 67 = 0
    u[8].z = 0u; u[8].w = 0u;               // cols 68..71 = 0
    uint4* dst = (uint4*)(featB + t * FSTR);
    #pragma unroll
    for (int i = 0; i < 9; ++i) dst[i] = u[i];
  }

  // ---- stage 1: D1[h][p] = W1 . feat   (A = W1 frags, B = feat frags) ----
  const f32x4 fz = {0.f, 0.f, 0.f, 0.f};
  f32x4 acc1[4][4];                          // [nt = h-tile][pt = point-tile]
  #pragma unroll
  for (int nt = 0; nt < 4; ++nt)
    #pragma unroll
    for (int pt = 0; pt < 4; ++pt) acc1[nt][pt] = fz;

  #pragma unroll
  for (int kt = 0; kt < 2; ++kt) {           // c = 0..63
    bf16x8 wa[4];
    #pragma unroll
    for (int nt = 0; nt < 4; ++nt)
      wa[nt] = ((const bf16x8*)W1F)[(kt*4 + nt)*64 + lane];
    bf16x8 bfv[4];
    #pragma unroll
    for (int pt = 0; pt < 4; ++pt)
      bfv[pt] = *(const bf16x8*)&featB[(w*64 + pt*16 + lr)*FSTR + kt*32 + quad*8];
    #pragma unroll
    for (int nt = 0; nt < 4; ++nt)
      #pragma unroll
      for (int pt = 0; pt < 4; ++pt)
        acc1[nt][pt] = MFMA32(wa[nt], bfv[pt], acc1[nt][pt]);
  }
  {                                          // tail c = 64..66 (A nonzero only quad 0, j<3)
    bf16x8 wa16[4];
    #pragma unroll
    for (int nt = 0; nt < 4; ++nt)
      wa16[nt] = ((const bf16x8*)W1F)[(8 + nt)*64 + lane];
    bf16x8 bt[4];
    #pragma unroll
    for (int pt = 0; pt < 4; ++pt)           // B slots j<8 <- cols 64..71; don't-cares hit zero A
      bt[pt] = *(const bf16x8*)&featB[(w*64 + pt*16 + lr)*FSTR + 64];
    #pragma unroll
    for (int nt = 0; nt < 4; ++nt)
      #pragma unroll
      for (int pt = 0; pt < 4; ++pt)
        acc1[nt][pt] = MFMA32(wa16[nt], bt[pt], acc1[nt][pt]);
  }

  // ---- bias + relu + pack -> hidden in LDS (overlay; wave-private; ds_write_b64) ----
  // lane (q,lr) holds h = nt*16+q*4+r for point col (pt*16+lr): H[point][h]
  #pragma unroll
  for (int nt = 0; nt < 4; ++nt) {
    const float4 bb = *(const float4*)(b1 + nt*16 + quad*4);
    #pragma unroll
    for (int pt = 0; pt < 4; ++pt) {
      const float v0 = fmaxf(acc1[nt][pt][0] + bb.x, 0.f);
      const float v1 = fmaxf(acc1[nt][pt][1] + bb.y, 0.f);
      const float v2 = fmaxf(acc1[nt][pt][2] + bb.z, 0.f);
      const float v3 = fmaxf(acc1[nt][pt][3] + bb.w, 0.f);
      uint2 d;
      d.x = (unsigned int)f2bf(v0) | ((unsigned int)f2bf(v1) << 16);
      d.y = (unsigned int)f2bf(v2) | ((unsigned int)f2bf(v3) << 16);
      *(uint2*)&featB[(w*64 + pt*16 + lr)*FSTR + nt*16 + quad*4] = d;
    }
  }

  // ---- stage 2 A-frags: A[m=lr][k=q*8+j] = H[point=pt*16+lr][h=kt*32+q*8+j] ----
  bf16x8 ah[4][2];
  #pragma unroll
  for (int pt = 0; pt < 4; ++pt)
    #pragma unroll
    for (int kt = 0; kt < 2; ++kt)
      ah[pt][kt] = *(const bf16x8*)&featB[(w*64 + pt*16 + lr)*FSTR + kt*32 + quad*8];

  // ---- stage 2: D2[point][o] = H . W2^T, full-K MFMAs; k-max; store ----
  #pragma unroll
  for (int ot = 0; ot < 8; ++ot) {
    const bf16x8 wb0 = ((const bf16x8*)W2F)[(0*8 + ot)*64 + lane];
    const bf16x8 wb1 = ((const bf16x8*)W2F)[(1*8 + ot)*64 + lane];
    f32x4 a2[4];
    #pragma unroll
    for (int pt = 0; pt < 4; ++pt) {
      a2[pt] = MFMA32(ah[pt][0], wb0, fz);
      a2[pt] = MFMA32(ah[pt][1], wb1, a2[pt]);
    }
    // k-max: rows m = q*4+r of tile pt are the 16 neighbors of m = w*4+pt
    float vm[4];
    #pragma unroll
    for (int pt = 0; pt < 4; ++pt) {
      float v = fmaxf(fmaxf(a2[pt][0], a2[pt][1]), fmaxf(a2[pt][2], a2[pt][3]));
      v = fmaxf(v, __shfl_xor(v, 16));
      v = fmaxf(v, __shfl_xor(v, 32));
      vm[pt] = v;
    }
    const float vq = (quad & 1) ? ((quad & 2) ? vm[3] : vm[1])
                                : ((quad & 2) ? vm[2] : vm[0]);
    const int o = ot*16 + lr;
    out[(size_t)o * MPTS + m0 + w*4 + quad] = vq + b2[o];
  }
}

// ---- fallback (ws too small): direct fp32 kernel, known-correct ----
__global__ __launch_bounds__(256) void pointnet_fallback(
    const float* __restrict__ x, const float* __restrict__ pos,
    const float* __restrict__ sup,
    const float* __restrict__ W1, const float* __restrict__ b1,
    const float* __restrict__ W2, const float* __restrict__ b2,
    const int* __restrict__ indices, float* __restrict__ out) {
  __shared__ float sfeat[16][68];
  __shared__ float shid[16][64];
  __shared__ float smax[4][128];
  __shared__ int sidx[16];
  const int t = threadIdx.x;
  const int m = blockIdx.x;
  if (t < 16) sidx[t] = indices[m*16 + t];
  const float sup0 = sup[m], sup1 = sup[MPTS + m], sup2 = sup[2*MPTS + m];
  __syncthreads();
  for (int u = t; u < 16*17; u += 256) {
    const int k = u / 17, c4 = (u - k*17) * 4;
    const int idx = sidx[k];
    float4 wv;
    if (c4 < 64) {
      wv.x = x[(size_t)(c4+0)*NPTS + idx]; wv.y = x[(size_t)(c4+1)*NPTS + idx];
      wv.z = x[(size_t)(c4+2)*NPTS + idx]; wv.w = x[(size_t)(c4+3)*NPTS + idx];
    } else {
      wv.x = pos[idx] - sup0; wv.y = pos[NPTS + idx] - sup1;
      wv.z = pos[2*NPTS + idx] - sup2; wv.w = 0.f;
    }
    *(float4*)&sfeat[k][c4] = wv;
  }
  const int h = t & 63, kg = t >> 6;
  float w1r[68];
  #pragma unroll
  for (int c = 0; c < 67; ++c) w1r[c] = W1[h*67 + c];
  w1r[67] = 0.f;
  const float bias1 = b1[h];
  __syncthreads();
  #pragma unroll
  for (int j = 0; j < 4; ++j) {
    const int k = kg*4 + j;
    float a = bias1;
    const float4* rr = (const float4*)sfeat[k];
    #pragma unroll
    for (int qq = 0; qq < 17; ++qq) {
      const float4 v = rr[qq];
      a += w1r[qq*4+0]*v.x + w1r[qq*4+1]*v.y + w1r[qq*4+2]*v.z + w1r[qq*4+3]*v.w;
    }
    shid[k][h] = fmaxf(a, 0.f);
  }
  const int ow = t & 63;
  float w2a[64], w2b[64];
  #pragma unroll
  for (int hh = 0; hh < 64; ++hh) { w2a[hh] = W2[ow*64 + hh]; w2b[hh] = W2[(ow+64)*64 + hh]; }
  __syncthreads();
  float mxa = -3.0e38f, mxb = -3.0e38f;
  #pragma unroll
  for (int j = 0; j < 4; ++j) {
    const int k = kg*4 + j;
    const float4* hr = (const float4*)shid[k];
    float pa = 0.f, pb = 0.f;
    #pragma unroll
    for (int qq = 0; qq < 16; ++qq) {
      const float4 v = hr[qq];
      pa += w2a[qq*4+0]*v.x + w2a[qq*4+1]*v.y + w2a[qq*4+2]*v.z + w2a[qq*4+3]*v.w;
      pb += w2b[qq*4+0]*v.x + w2b[qq*4+1]*v.y + w2b[qq*4+2]*v.z + w2b[qq*4+3]*v.w;
    }
    mxa = fmaxf(mxa, pa); mxb = fmaxf(mxb, pb);
  }
  smax[kg][ow] = mxa; smax[kg][64 + ow] = mxb;
  __syncthreads();
  if (t < 128) {
    out[(size_t)t * MPTS + m] =
        fmaxf(fmaxf(smax[0][t], smax[1][t]), fmaxf(smax[2][t], smax[3][t])) + b2[t];
  }
}

extern "C" void kernel_launch(void* const* d_in, const int* in_sizes, int n_in,
                              void* d_out, int out_size, void* d_ws, size_t ws_size,
                              hipStream_t stream) {
  const float* x   = (const float*)d_in[0];
  const float* pos = (const float*)d_in[1];
  const float* sup = (const float*)d_in[2];
  const float* W1  = (const float*)d_in[3];
  const float* b1  = (const float*)d_in[4];
  const float* W2  = (const float*)d_in[5];
  const float* b2  = (const float*)d_in[6];
  const int* indices = (const int*)d_in[7];
  float* out = (float*)d_out;

  const size_t P2_BYTES  = (size_t)NPTS * FSTR * 2;   // 9,437,184
  const size_t W1F_BYTES = 12 * 64 * 8 * 2;           // 12,288
  const size_t W2F_BYTES = 16 * 64 * 8 * 2;           // 16,384
  if (ws_size >= P2_BYTES + W1F_BYTES + W2F_BYTES) {
    unsigned short* P2  = (unsigned short*)d_ws;
    unsigned short* W1F = (unsigned short*)((char*)d_ws + P2_BYTES);
    unsigned short* W2F = (unsigned short*)((char*)d_ws + P2_BYTES + W1F_BYTES);
    pack_all<<<NPTS/64, 256, 0, stream>>>(x, pos, W1, W2, P2, W1F, W2F);
    pointnet_mfma<<<MPTS/16, 256, 0, stream>>>(P2, sup, W1F, b1, W2F, b2, indices, out);
  } else {
    pointnet_fallback<<<MPTS, 256, 0, stream>>>(x, pos, sup, W1, b1, W2, b2, indices, out);
  }
}

// Round 7
// 142.887 us; speedup vs baseline: 1.0895x; 1.0315x over previous
//
#include <hip/hip_runtime.h>

#define NPTS 65536
#define MPTS 65536

typedef __attribute__((ext_vector_type(8))) short bf16x8;
typedef __attribute__((ext_vector_type(4))) float f32x4;

__device__ __forceinline__ float bflo(unsigned int u){ union{unsigned int i; float f;} v; v.i = u<<16; return v.f; }
__device__ __forceinline__ float bfhi(unsigned int u){ union{unsigned int i; float f;} v; v.i = u & 0xffff0000u; return v.f; }
__device__ __forceinline__ unsigned short f2bf(float f){
  union{float f; unsigned int i;} v; v.f=f;
  unsigned int r = v.i + 0x7fffu + ((v.i>>16)&1u);  // RNE
  return (unsigned short)(r>>16);
}
__device__ __forceinline__ unsigned int pk2(float a, float b){
  return (unsigned int)f2bf(a) | ((unsigned int)f2bf(b) << 16);
}

#define MFMA32(a,b,c) __builtin_amdgcn_mfma_f32_16x16x32_bf16((a),(b),(c),0,0,0)

// ---- weight fragment images (grid 7 x 256) ----
// W1F: 12 frags (kt0..1 x nt0..3 main, + 4 tail frags c=64..66); W2F: 16 frags full-K
__global__ __launch_bounds__(256) void pack_w(
    const float* __restrict__ W1, const float* __restrict__ W2,
    unsigned short* __restrict__ W1F, unsigned short* __restrict__ W2F) {
  const int wid = blockIdx.x * 256 + threadIdx.x;
  if (wid < 768) {
    const int f = wid >> 6, lane = wid & 63;
    const int q = lane >> 4, lr = lane & 15;
    if (f < 8) {
      const int kt = f >> 2, nt = f & 3;
      #pragma unroll
      for (int j = 0; j < 8; ++j)
        W1F[wid*8 + j] = f2bf(W1[(nt*16 + lr)*67 + kt*32 + q*8 + j]);
    } else {
      const int nt = f - 8;
      #pragma unroll
      for (int j = 0; j < 8; ++j) {
        const int c = 64 + q*4 + j;
        W1F[wid*8 + j] = (j < 4 && c < 67) ? f2bf(W1[(nt*16 + lr)*67 + c]) : (unsigned short)0;
      }
    }
  } else if (wid < 768 + 1024) {
    const int gg = wid - 768;
    const int g = gg >> 6, lane = gg & 63;
    const int q = lane >> 4, lr = lane & 15;
    const int kt = g >> 3, ot = g & 7;
    #pragma unroll
    for (int j = 0; j < 8; ++j)
      W2F[gg*8 + j] = f2bf(W2[(ot*16 + lr)*64 + kt*32 + q*8 + j]);
  }
}

// ---- pack_u: U[n][64] = bf16( W1 . [x_n; pos_n] + b1 )  (pre-relu, pre-support) ----
// Dense MFMA GEMM, no gather, no LDS, no barriers. Grid 256 x 256thr, 64 pts/wave.
__global__ __launch_bounds__(256) void pack_u(
    const float* __restrict__ x,     // [64][N]
    const float* __restrict__ pos,   // [3][N]
    const unsigned short* __restrict__ W1F,
    const float* __restrict__ b1,
    unsigned short* __restrict__ U) { // [N][64] bf16
  const int t = threadIdx.x;
  const int lane = t & 63, w = t >> 6, quad = lane >> 4, lr = lane & 15;
  const int nb = blockIdx.x * 256 + w * 64;

  bf16x8 wa[2][4], wt[4];
  #pragma unroll
  for (int kt = 0; kt < 2; ++kt)
    #pragma unroll
    for (int nt = 0; nt < 4; ++nt)
      wa[kt][nt] = ((const bf16x8*)W1F)[(kt*4 + nt)*64 + lane];
  #pragma unroll
  for (int nt = 0; nt < 4; ++nt)
    wt[nt] = ((const bf16x8*)W1F)[(8 + nt)*64 + lane];

  const f32x4 fz = {0.f, 0.f, 0.f, 0.f};
  f32x4 acc[4][4];                     // [nt][pt]
  #pragma unroll
  for (int nt = 0; nt < 4; ++nt)
    #pragma unroll
    for (int pt = 0; pt < 4; ++pt) acc[nt][pt] = fz;

  #pragma unroll
  for (int kt = 0; kt < 2; ++kt) {     // B-frag direct from channel-major x (coalesced in lr)
    bf16x8 bfr[4];
    #pragma unroll
    for (int pt = 0; pt < 4; ++pt) {
      const float* xc = x + (size_t)(kt*32 + quad*8) * NPTS + nb + pt*16 + lr;
      union { unsigned int d[4]; bf16x8 v; } mk;
      #pragma unroll
      for (int i = 0; i < 4; ++i)
        mk.d[i] = pk2(xc[(size_t)(2*i) * NPTS], xc[(size_t)(2*i + 1) * NPTS]);
      bfr[pt] = mk.v;
    }
    #pragma unroll
    for (int nt = 0; nt < 4; ++nt)
      #pragma unroll
      for (int pt = 0; pt < 4; ++pt)
        acc[nt][pt] = MFMA32(wa[kt][nt], bfr[pt], acc[nt][pt]);
  }
  {                                    // tail c=64..66: pos (A zero except quad0,j<3)
    bf16x8 btr[4];
    #pragma unroll
    for (int pt = 0; pt < 4; ++pt) {
      const int n = nb + pt*16 + lr;
      union { unsigned int d[4]; bf16x8 v; } mk;
      mk.d[0] = pk2(pos[n], pos[NPTS + n]);
      mk.d[1] = (unsigned int)f2bf(pos[2*NPTS + n]);
      mk.d[2] = 0u; mk.d[3] = 0u;
      btr[pt] = mk.v;
    }
    #pragma unroll
    for (int nt = 0; nt < 4; ++nt)
      #pragma unroll
      for (int pt = 0; pt < 4; ++pt)
        acc[nt][pt] = MFMA32(wt[nt], btr[pt], acc[nt][pt]);
  }
  // bias + pack + store: lane holds h = nt*16+quad*4+r for point col lr
  #pragma unroll
  for (int nt = 0; nt < 4; ++nt) {
    const float4 bb = *(const float4*)(b1 + nt*16 + quad*4);
    #pragma unroll
    for (int pt = 0; pt < 4; ++pt) {
      const int n = nb + pt*16 + lr;
      uint2 d;
      d.x = pk2(acc[nt][pt][0] + bb.x, acc[nt][pt][1] + bb.y);
      d.y = pk2(acc[nt][pt][2] + bb.z, acc[nt][pt][3] + bb.w);
      *(uint2*)(U + (size_t)n * 64 + nt*16 + quad*4) = d;
    }
  }
}

// ---- main: gather U -> h=relu(u - W1p.sup) in-register -> MLP2 MFMA -> max-K ----
__global__ __launch_bounds__(256, 4) void pointnet_mfma2(
    const unsigned short* __restrict__ U,    // [N][64] bf16
    const float* __restrict__ sup,           // [3][M]
    const float* __restrict__ W1,            // [64][67] (for W1p columns 64..66)
    const unsigned short* __restrict__ W2F,
    const float* __restrict__ b2,
    const int* __restrict__ indices,         // [M][16]
    float* __restrict__ out) {               // [128][M]
  __shared__ __align__(16) unsigned short featB[256 * 72];  // 36,864 B -> 4 blocks/CU

  const int t = threadIdx.x;
  const int m0 = blockIdx.x * 16;
  const int lane = t & 63, w = t >> 6, quad = lane >> 4, lr = lane & 15;

  // gather: thread t owns point t; 128-B aligned row = exactly one L2 line
  {
    const int idx = indices[m0*16 + t];
    const uint4* src = (const uint4*)(U + (size_t)idx * 64);
    uint4 u[8];
    #pragma unroll
    for (int i = 0; i < 8; ++i) u[i] = src[i];
    uint4* dst = (uint4*)(featB + t * 72);
    #pragma unroll
    for (int i = 0; i < 8; ++i) dst[i] = u[i];
  }

  // W1p rows for this lane's k-slots: h = kt*32 + quad*8 + j  (L2-hot broadcast)
  float w1p[16][3];
  #pragma unroll
  for (int kt = 0; kt < 2; ++kt)
    #pragma unroll
    for (int j = 0; j < 8; ++j) {
      const float* r = W1 + (size_t)(kt*32 + quad*8 + j) * 67 + 64;
      w1p[kt*8+j][0] = r[0]; w1p[kt*8+j][1] = r[1]; w1p[kt*8+j][2] = r[2];
    }

  // build stage-2 A-frags: h = relu(u - v_m), v computed in-register
  bf16x8 ah[4][2];
  #pragma unroll
  for (int pt = 0; pt < 4; ++pt) {
    const int m = m0 + w*4 + pt;
    const float s0 = sup[m], s1 = sup[MPTS + m], s2 = sup[2*MPTS + m];
    #pragma unroll
    for (int kt = 0; kt < 2; ++kt) {
      const uint4 ur = *(const uint4*)&featB[(w*64 + pt*16 + lr)*72 + kt*32 + quad*8];
      const unsigned int uu[4] = {ur.x, ur.y, ur.z, ur.w};
      union { unsigned int d[4]; bf16x8 v; } mk;
      #pragma unroll
      for (int i = 0; i < 4; ++i) {
        const float* wl = w1p[kt*8 + 2*i];
        const float* wh = w1p[kt*8 + 2*i + 1];
        const float vl = wl[0]*s0 + wl[1]*s1 + wl[2]*s2;
        const float vh = wh[0]*s0 + wh[1]*s1 + wh[2]*s2;
        const float hl = fmaxf(bflo(uu[i]) - vl, 0.f);
        const float hh = fmaxf(bfhi(uu[i]) - vh, 0.f);
        mk.d[i] = pk2(hl, hh);
      }
      ah[pt][kt] = mk.v;
    }
  }

  // stage 2: D2[point][o], full-K; k-max across rows; direct store
  const f32x4 fz = {0.f, 0.f, 0.f, 0.f};
  #pragma unroll
  for (int ot = 0; ot < 8; ++ot) {
    const bf16x8 wb0 = ((const bf16x8*)W2F)[(0*8 + ot)*64 + lane];
    const bf16x8 wb1 = ((const bf16x8*)W2F)[(1*8 + ot)*64 + lane];
    f32x4 a2[4];
    #pragma unroll
    for (int pt = 0; pt < 4; ++pt) {
      a2[pt] = MFMA32(ah[pt][0], wb0, fz);
      a2[pt] = MFMA32(ah[pt][1], wb1, a2[pt]);
    }
    float vm[4];
    #pragma unroll
    for (int pt = 0; pt < 4; ++pt) {
      float v = fmaxf(fmaxf(a2[pt][0], a2[pt][1]), fmaxf(a2[pt][2], a2[pt][3]));
      v = fmaxf(v, __shfl_xor(v, 16));
      v = fmaxf(v, __shfl_xor(v, 32));
      vm[pt] = v;
    }
    const float vq = (quad & 1) ? ((quad & 2) ? vm[3] : vm[1])
                                : ((quad & 2) ? vm[2] : vm[0]);
    const int o = ot*16 + lr;
    out[(size_t)o * MPTS + m0 + w*4 + quad] = vq + b2[o];
  }
}

// ---- fallback (ws too small): direct fp32 kernel, known-correct ----
__global__ __launch_bounds__(256) void pointnet_fallback(
    const float* __restrict__ x, const float* __restrict__ pos,
    const float* __restrict__ sup,
    const float* __restrict__ W1, const float* __restrict__ b1,
    const float* __restrict__ W2, const float* __restrict__ b2,
    const int* __restrict__ indices, float* __restrict__ out) {
  __shared__ float sfeat[16][68];
  __shared__ float shid[16][64];
  __shared__ float smax[4][128];
  __shared__ int sidx[16];
  const int t = threadIdx.x;
  const int m = blockIdx.x;
  if (t < 16) sidx[t] = indices[m*16 + t];
  const float sup0 = sup[m], sup1 = sup[MPTS + m], sup2 = sup[2*MPTS + m];
  __syncthreads();
  for (int u = t; u < 16*17; u += 256) {
    const int k = u / 17, c4 = (u - k*17) * 4;
    const int idx = sidx[k];
    float4 wv;
    if (c4 < 64) {
      wv.x = x[(size_t)(c4+0)*NPTS + idx]; wv.y = x[(size_t)(c4+1)*NPTS + idx];
      wv.z = x[(size_t)(c4+2)*NPTS + idx]; wv.w = x[(size_t)(c4+3)*NPTS + idx];
    } else {
      wv.x = pos[idx] - sup0; wv.y = pos[NPTS + idx] - sup1;
      wv.z = pos[2*NPTS + idx] - sup2; wv.w = 0.f;
    }
    *(float4*)&sfeat[k][c4] = wv;
  }
  const int h = t & 63, kg = t >> 6;
  float w1r[68];
  #pragma unroll
  for (int c = 0; c < 67; ++c) w1r[c] = W1[h*67 + c];
  w1r[67] = 0.f;
  const float bias1 = b1[h];
  __syncthreads();
  #pragma unroll
  for (int j = 0; j < 4; ++j) {
    const int k = kg*4 + j;
    float a = bias1;
    const float4* rr = (const float4*)sfeat[k];
    #pragma unroll
    for (int qq = 0; qq < 17; ++qq) {
      const float4 v = rr[qq];
      a += w1r[qq*4+0]*v.x + w1r[qq*4+1]*v.y + w1r[qq*4+2]*v.z + w1r[qq*4+3]*v.w;
    }
    shid[k][h] = fmaxf(a, 0.f);
  }
  const int ow = t & 63;
  float w2a[64], w2b[64];
  #pragma unroll
  for (int hh = 0; hh < 64; ++hh) { w2a[hh] = W2[ow*64 + hh]; w2b[hh] = W2[(ow+64)*64 + hh]; }
  __syncthreads();
  float mxa = -3.0e38f, mxb = -3.0e38f;
  #pragma unroll
  for (int j = 0; j < 4; ++j) {
    const int k = kg*4 + j;
    const float4* hr = (const float4*)shid[k];
    float pa = 0.f, pb = 0.f;
    #pragma unroll
    for (int qq = 0; qq < 16; ++qq) {
      const float4 v = hr[qq];
      pa += w2a[qq*4+0]*v.x + w2a[qq*4+1]*v.y + w2a[qq*4+2]*v.z + w2a[qq*4+3]*v.w;
      pb += w2b[qq*4+0]*v.x + w2b[qq*4+1]*v.y + w2b[qq*4+2]*v.z + w2b[qq*4+3]*v.w;
    }
    mxa = fmaxf(mxa, pa); mxb = fmaxf(mxb, pb);
  }
  smax[kg][ow] = mxa; smax[kg][64 + ow] = mxb;
  __syncthreads();
  if (t < 128) {
    out[(size_t)t * MPTS + m] =
        fmaxf(fmaxf(smax[0][t], smax[1][t]), fmaxf(smax[2][t], smax[3][t])) + b2[t];
  }
}

extern "C" void kernel_launch(void* const* d_in, const int* in_sizes, int n_in,
                              void* d_out, int out_size, void* d_ws, size_t ws_size,
                              hipStream_t stream) {
  const float* x   = (const float*)d_in[0];
  const float* pos = (const float*)d_in[1];
  const float* sup = (const float*)d_in[2];
  const float* W1  = (const float*)d_in[3];
  const float* b1  = (const float*)d_in[4];
  const float* W2  = (const float*)d_in[5];
  const float* b2  = (const float*)d_in[6];
  const int* indices = (const int*)d_in[7];
  float* out = (float*)d_out;

  const size_t U_BYTES   = (size_t)NPTS * 64 * 2;     // 8,388,608
  const size_t W1F_BYTES = 12 * 64 * 8 * 2;           // 12,288
  const size_t W2F_BYTES = 16 * 64 * 8 * 2;           // 16,384
  if (ws_size >= U_BYTES + W1F_BYTES + W2F_BYTES) {
    unsigned short* U   = (unsigned short*)d_ws;
    unsigned short* W1F = (unsigned short*)((char*)d_ws + U_BYTES);
    unsigned short* W2F = (unsigned short*)((char*)d_ws + U_BYTES + W1F_BYTES);
    pack_w<<<7, 256, 0, stream>>>(W1, W2, W1F, W2F);
    pack_u<<<NPTS/256, 256, 0, stream>>>(x, pos, W1F, b1, U);
    pointnet_mfma2<<<MPTS/16, 256, 0, stream>>>(U, sup, W1, W2F, b2, indices, out);
  } else {
    pointnet_fallback<<<MPTS, 256, 0, stream>>>(x, pos, sup, W1, b1, W2, b2, indices, out);
  }
}